// Round 4
// baseline (308.276 us; speedup 1.0000x reference)
//
#include <hip/hip_runtime.h>
#include <math.h>

// AFT attention, round 4.
// Bottleneck analysis (r3): LDS pipe-bound (28 LDS instr per 8 MFMA per dy).
// Fixes: (1) weight Toeplitz B-fragments precomputed per channel into global
// scratch (image-independent!), loaded as 4 coalesced dwordx4/dy -> zero LDS;
// (2) image stored quad-permuted within 16-col groups so each A fragment is
// ONE ds_read_b128; row stride 104 f16 = 208 B (16B-aligned, conflict-free
// b128 phases); (3) both conv passes fused in one dy loop (B amortized 2x).

#define C_     192
#define BS_    16
#define HW_    4096
#define KS_    31
#define NT_    128

#define IROWS_ 94
#define ISTR_  104                  // f16 per row (208 B)
#define IMGSZ_ (IROWS_ * ISTR_)     // 9776 f16 per image
#define NFRAG_ 160                  // per dy: l5(2) x s81(80)
#define BF_PER_C_ (KS_ * NFRAG_ * 8)             // 39,680 f16 per channel
#define BF_BYTES_ ((size_t)C_ * BF_PER_C_ * 2)   // 15,237,120 B

typedef _Float16 f16;
typedef _Float16 f16x4 __attribute__((ext_vector_type(4)));
typedef _Float16 f16x8 __attribute__((ext_vector_type(8)));
typedef float    f32x16 __attribute__((ext_vector_type(16)));

// ---------------------------------------------------------------- build B ----
// frag fi = ((c*31 + dy)*2 + l5)*80 + s81, s = s81-31 = 16*kc - l31.
// slot j holds w[dy][s + 4*l5 + (j&3) + 8*(j>>2) - 1] (0 outside [0,31)).
__global__ __launch_bounds__(256)
void build_bfrags(const float* __restrict__ wts, f16* __restrict__ bf)
{
    const int fi = blockIdx.x * 256 + threadIdx.x;
    if (fi >= C_ * KS_ * NFRAG_) return;
    const int s81 = fi % 80;
    int rest = fi / 80;
    const int l5 = rest & 1; rest >>= 1;
    const int dy = rest % KS_;
    const int c  = rest / KS_;
    const float* wrow = wts + (size_t)c * (KS_ * KS_) + dy * KS_;
    const int s = s81 - 31;
    f16x8 o;
#pragma unroll
    for (int j = 0; j < 8; ++j) {
        const int tap = s + 4 * l5 + (j & 3) + 8 * (j >> 2) - 1;
        o[j] = (tap >= 0 && tap < KS_) ? (f16)expm1f(wrow[tap]) : (f16)0.f;
    }
    *reinterpret_cast<f16x8*>(bf + (size_t)fi * 8) = o;
}

// ------------------------------------------------------------- main (fast) ---
__global__ __launch_bounds__(NT_, 2)
void aft_mfma2(const float* __restrict__ qkv,
               const f16* __restrict__ bf,
               float* __restrict__ out)
{
    __shared__ __align__(16) f16 IMG[2 * IMGSZ_];   // [0]=e image, [1]=kv image
    __shared__ float red[8];

    const int blk = blockIdx.x;
    const int c = blk >> 4;                 // c-major: 16 consecutive blocks share bf[c]
    const int b = blk & 15;
    const float* qrow = qkv + ((size_t)b * (3 * C_) + c) * HW_;
    const float* krow = qrow + (size_t)C_ * HW_;
    const float* vrow = qrow + (size_t)(2 * C_) * HW_;
    float*       orow = out + ((size_t)b * C_ + c) * HW_;

    const int t = threadIdx.x, lane = t & 63, wid = t >> 6;
    const int l5 = lane >> 5, l31 = lane & 31;

    // zero both images (pads must be 0)
    uint4* I4 = reinterpret_cast<uint4*>(IMG);
    for (int i = t; i < (2 * IMGSZ_) / 8; i += NT_) I4[i] = make_uint4(0u, 0u, 0u, 0u);

    // ---- phase 1: softmax max ----
    float pm = -3.0e38f;
#pragma unroll
    for (int i = 0; i < 8; ++i) {
        float4 k4 = ((const float4*)krow)[t + NT_ * i];
        pm = fmaxf(pm, fmaxf(fmaxf(k4.x, k4.y), fmaxf(k4.z, k4.w)));
    }
#pragma unroll
    for (int s = 32; s; s >>= 1) pm = fmaxf(pm, __shfl_xor(pm, s));
    if (lane == 0) red[wid] = pm;
    __syncthreads();                        // fences zero-fill too
    const float m = fmaxf(red[0], red[1]);

    // ---- phase 2: e = exp(k-m), kv = e*v -> permuted f16 images; Z, sumkv ----
    const int ry  = t >> 4;                 // image row comp 0..7
    const int rx4 = t & 15;                 // float4 slot in 64-wide row
    const int g   = 1 + (rx4 >> 2);         // 16-col group (data starts col 16)
    const int q   = rx4 & 3;
    const int qp  = (q == 1) ? 2 : (q == 2) ? 1 : q;   // quad permutation 0,2,1,3
    float zs = 0.f, skv = 0.f;
#pragma unroll
    for (int i = 0; i < 8; ++i) {
        float4 k4 = ((const float4*)krow)[t + NT_ * i];
        float4 v4 = ((const float4*)vrow)[t + NT_ * i];
        float e0 = __expf(k4.x - m), e1 = __expf(k4.y - m);
        float e2 = __expf(k4.z - m), e3 = __expf(k4.w - m);
        zs += (e0 + e1) + (e2 + e3);
        float a0 = e0 * v4.x, a1 = e1 * v4.y, a2 = e2 * v4.z, a3 = e3 * v4.w;
        skv += (a0 + a1) + (a2 + a3);
        const int row = ry + 8 * i + 15;
        f16* pE = (f16*)((char*)IMG + row * (ISTR_ * 2) + g * 32 + qp * 8);
        f16x4 he; he[0] = (f16)e0; he[1] = (f16)e1; he[2] = (f16)e2; he[3] = (f16)e3;
        f16x4 hk; hk[0] = (f16)a0; hk[1] = (f16)a1; hk[2] = (f16)a2; hk[3] = (f16)a3;
        *reinterpret_cast<f16x4*>(pE) = he;
        *reinterpret_cast<f16x4*>(pE + IMGSZ_) = hk;
    }
#pragma unroll
    for (int s = 32; s; s >>= 1) { zs += __shfl_xor(zs, s); skv += __shfl_xor(skv, s); }
    if (lane == 0) { red[2 + wid] = zs; red[4 + wid] = skv; }
    __syncthreads();                        // images + sums ready
    const float Z     = red[2] + red[3];
    const float sumkv = red[4] + red[5];

    // ---- fused conv loop over dy: 16 MFMAs, 12 ds_read_b128, 4 global b128 ----
    f32x16 aE0, aE1, aK0, aK1;
#pragma unroll
    for (int r = 0; r < 16; ++r) { aE0[r] = 0.f; aE1[r] = 0.f; aK0[r] = 0.f; aK1[r] = 0.f; }

    const f16* bl = bf + (size_t)c * BF_PER_C_ + l5 * 640 + (31 - l31) * 8;
    int abyte = ((32 * wid) + l31) * (ISTR_ * 2) + l5 * 16;

    f16x8 Bc[4];
#pragma unroll
    for (int kc = 0; kc < 4; ++kc)
        Bc[kc] = *reinterpret_cast<const f16x8*>(bl + kc * 128);

#pragma unroll 1
    for (int dy = 0; dy < KS_; ++dy) {
        // prefetch next-dy B (global, L2-hot)
        const int dyn = (dy + 1 < KS_) ? dy + 1 : dy;
        const f16* bln = bl + dyn * (NFRAG_ * 8);
        f16x8 Bn[4];
#pragma unroll
        for (int kc = 0; kc < 4; ++kc)
            Bn[kc] = *reinterpret_cast<const f16x8*>(bln + kc * 128);

        f16x8 AE[6], AK[6];
        const char* ap = (const char*)IMG + abyte;
#pragma unroll
        for (int cc = 0; cc < 6; ++cc) {
            AE[cc] = *reinterpret_cast<const f16x8*>(ap + cc * 32);
            AK[cc] = *reinterpret_cast<const f16x8*>(ap + cc * 32 + IMGSZ_ * 2);
        }
#pragma unroll
        for (int kc = 0; kc < 4; ++kc) {
            aE0 = __builtin_amdgcn_mfma_f32_32x32x16_f16(AE[kc],     Bc[kc], aE0, 0, 0, 0);
            aE1 = __builtin_amdgcn_mfma_f32_32x32x16_f16(AE[kc + 2], Bc[kc], aE1, 0, 0, 0);
            aK0 = __builtin_amdgcn_mfma_f32_32x32x16_f16(AK[kc],     Bc[kc], aK0, 0, 0, 0);
            aK1 = __builtin_amdgcn_mfma_f32_32x32x16_f16(AK[kc + 2], Bc[kc], aK1, 0, 0, 0);
        }
#pragma unroll
        for (int kc = 0; kc < 4; ++kc) Bc[kc] = Bn[kc];
        abyte += ISTR_ * 2;
    }

    // ---- epilogue: out = (kv_c + sumkv) / ((k_c + Z(1+1e-8)) * (1+e^-q)) ----
    const int yb = 32 * wid + 4 * l5;
#pragma unroll
    for (int tt = 0; tt < 2; ++tt) {
        const f32x16& ke = tt ? aE1 : aE0;
        const f32x16& kv = tt ? aK1 : aK0;
        const int x = 32 * tt + l31;
#pragma unroll
        for (int r = 0; r < 16; ++r) {
            const int y = yb + (r & 3) + 8 * (r >> 2);
            const int idx = y * 64 + x;
            const float qv = qrow[idx];
            const float den = (ke[r] + Z + Z * 1e-8f) * (1.f + __expf(-qv));
            orow[idx] = (kv[r] + sumkv) * __builtin_amdgcn_rcpf(den);
        }
    }
}

// ------------------------------------------- fallback (round-3, ws too small)
#define FB_IROWS_ 94
#define FB_ISTR_  100
#define FB_WCOLS_ 96

__device__ __forceinline__ void conv_pass_fb(const f16* __restrict__ img,
                                             const unsigned int* __restrict__ wp,
                                             int lane, int ybase,
                                             f32x16* acc0, f32x16* acc1)
{
    const int l5  = lane >> 5;
    const int l31 = lane & 31;
    int aoff = (ybase + l31) * FB_ISTR_ + 4 * l5;
    const unsigned int* bp0 = wp + (32 + 4 * l5 - l31);
#pragma unroll 1
    for (int dy = 0; dy < KS_; ++dy) {
        f16x8 A[6];
        const f16* ap = img + aoff;
#pragma unroll
        for (int cc = 0; cc < 6; ++cc) {
            f16x4 lo = *(const f16x4*)(ap + cc * 16);
            f16x4 hi = *(const f16x4*)(ap + cc * 16 + 8);
            A[cc] = __builtin_shufflevector(lo, hi, 0, 1, 2, 3, 4, 5, 6, 7);
        }
        const unsigned int* bp = bp0 + dy * FB_WCOLS_;
#pragma unroll
        for (int kc = 0; kc < 4; ++kc) {
            uint4 bw;
            bw.x = bp[kc * 16 + 0];
            bw.y = bp[kc * 16 + 2];
            bw.z = bp[kc * 16 + 8];
            bw.w = bp[kc * 16 + 10];
            f16x8 B = __builtin_bit_cast(f16x8, bw);
            *acc0 = __builtin_amdgcn_mfma_f32_32x32x16_f16(A[kc],     B, *acc0, 0, 0, 0);
            *acc1 = __builtin_amdgcn_mfma_f32_32x32x16_f16(A[kc + 2], B, *acc1, 0, 0, 0);
        }
        aoff += FB_ISTR_;
    }
}

__global__ __launch_bounds__(NT_, 2)
void aft_mfma(const float* __restrict__ qkv,
              const float* __restrict__ wts,
              float* __restrict__ out)
{
    __shared__ __align__(16) f16 IMGF[FB_IROWS_ * FB_ISTR_];
    __shared__ unsigned int WP[KS_ * FB_WCOLS_];
    __shared__ float red[8];

    const int bc = blockIdx.x;
    const int b  = bc / C_;
    const int c  = bc - b * C_;
    const float* qrow = qkv + ((size_t)b * (3 * C_) + c) * HW_;
    const float* krow = qrow + (size_t)C_ * HW_;
    const float* vrow = qrow + (size_t)(2 * C_) * HW_;
    float*       orow = out + ((size_t)b * C_ + c) * HW_;

    const int t = threadIdx.x, lane = t & 63, wid = t >> 6;

    unsigned int* IMGu = (unsigned int*)IMGF;
    for (int i = t; i < (FB_IROWS_ * FB_ISTR_) / 2; i += NT_) IMGu[i] = 0u;
    const float* wch = wts + (size_t)c * (KS_ * KS_);
    for (int i = t; i < KS_ * FB_WCOLS_; i += NT_) {
        const int dy = i / FB_WCOLS_, cw = i - dy * FB_WCOLS_;
        const int d0 = cw - 33, d1 = cw - 32;
        const float w0 = (d0 >= 0 && d0 < KS_) ? expm1f(wch[dy * KS_ + d0]) : 0.f;
        const float w1 = (d1 >= 0 && d1 < KS_) ? expm1f(wch[dy * KS_ + d1]) : 0.f;
        union { unsigned int u; f16 h[2]; } pk;
        pk.h[0] = (f16)w0; pk.h[1] = (f16)w1;
        WP[i] = pk.u;
    }

    float kvv[32];
    float pm = -3.0e38f;
#pragma unroll
    for (int i = 0; i < 8; ++i) {
        float4 v = ((const float4*)krow)[t + NT_ * i];
        kvv[4*i+0] = v.x; kvv[4*i+1] = v.y; kvv[4*i+2] = v.z; kvv[4*i+3] = v.w;
        pm = fmaxf(pm, fmaxf(fmaxf(v.x, v.y), fmaxf(v.z, v.w)));
    }
#pragma unroll
    for (int s = 32; s; s >>= 1) pm = fmaxf(pm, __shfl_xor(pm, s));
    if (lane == 0) red[wid] = pm;
    __syncthreads();
    const float m = fmaxf(red[0], red[1]);

    const int ry = t >> 4;
    const int rx = (t & 15) * 4;
    float ps = 0.f;
#pragma unroll
    for (int i = 0; i < 8; ++i) {
        f16x4 h;
#pragma unroll
        for (int e = 0; e < 4; ++e) {
            float ev = __expf(kvv[4*i+e] - m);
            ps += ev;
            h[e] = (f16)ev;
        }
        *(f16x4*)(&IMGF[(ry + 8 * i + 15) * FB_ISTR_ + rx + 16]) = h;
    }
#pragma unroll
    for (int s = 32; s; s >>= 1) ps += __shfl_xor(ps, s);
    if (lane == 0) red[2 + wid] = ps;
    __syncthreads();
    const float Z = red[2] + red[3];

    f32x16 accA0, accA1;
#pragma unroll
    for (int r = 0; r < 16; ++r) { accA0[r] = 0.f; accA1[r] = 0.f; }
    conv_pass_fb(IMGF, WP, lane, 32 * wid, &accA0, &accA1);
    __syncthreads();

    float skv = 0.f;
#pragma unroll
    for (int i = 0; i < 8; ++i) {
        float4 v = ((const float4*)vrow)[t + NT_ * i];
        f16* pp = &IMGF[(ry + 8 * i + 15) * FB_ISTR_ + rx + 16];
        f16x4 h = *(f16x4*)pp;
        float a0 = (float)h[0] * v.x;
        float a1 = (float)h[1] * v.y;
        float a2 = (float)h[2] * v.z;
        float a3 = (float)h[3] * v.w;
        skv += (a0 + a1) + (a2 + a3);
        h[0] = (f16)a0; h[1] = (f16)a1; h[2] = (f16)a2; h[3] = (f16)a3;
        *(f16x4*)pp = h;
    }
#pragma unroll
    for (int s = 32; s; s >>= 1) skv += __shfl_xor(skv, s);
    if (lane == 0) red[4 + wid] = skv;
    __syncthreads();
    const float sumkv = red[4] + red[5];

    f32x16 accB0, accB1;
#pragma unroll
    for (int r = 0; r < 16; ++r) { accB0[r] = 0.f; accB1[r] = 0.f; }
    conv_pass_fb(IMGF, WP, lane, 32 * wid, &accB0, &accB1);

    const int yb = 32 * wid + 4 * (lane >> 5);
    const int l31 = lane & 31;
#pragma unroll
    for (int tt = 0; tt < 2; ++tt) {
        const f32x16& ka = tt ? accA1 : accA0;
        const f32x16& va = tt ? accB1 : accB0;
        const int x = 32 * tt + l31;
#pragma unroll
        for (int r = 0; r < 16; ++r) {
            const int y = yb + (r & 3) + 8 * (r >> 2);
            const int idx = y * 64 + x;
            const float qv = qrow[idx];
            const float den = (ka[r] + Z + Z * 1e-8f) * (1.f + __expf(-qv));
            orow[idx] = (va[r] + sumkv) * __builtin_amdgcn_rcpf(den);
        }
    }
}

// ------------------------------------------------------------------ launch ---
extern "C" void kernel_launch(void* const* d_in, const int* in_sizes, int n_in,
                              void* d_out, int out_size, void* d_ws, size_t ws_size,
                              hipStream_t stream)
{
    const float* qkv = (const float*)d_in[0];   // (16, 576, 4096) fp32
    const float* wts = (const float*)d_in[1];   // (192, 1, 31, 31) fp32
    float* out       = (float*)d_out;           // (16, 192, 4096) fp32
    (void)in_sizes; (void)n_in; (void)out_size;

    if (ws_size >= BF_BYTES_ && d_ws != nullptr) {
        f16* bfr = (f16*)d_ws;
        const int total = C_ * KS_ * NFRAG_;
        build_bfrags<<<dim3((total + 255) / 256), dim3(256), 0, stream>>>(wts, bfr);
        aft_mfma2<<<dim3(BS_ * C_), dim3(NT_), 0, stream>>>(qkv, bfr, out);
    } else {
        aft_mfma<<<dim3(BS_ * C_), dim3(NT_), 0, stream>>>(qkv, wts, out);
    }
}

// Round 5
// 282.898 us; speedup vs baseline: 1.0897x; 1.0897x over previous
//
#include <hip/hip_runtime.h>
#include <math.h>

// AFT attention, round 5.
// r4 post-mortem: latency-bound at 18% occupancy (no pipe >30%). Fixes:
// (1) 4 waves/block with dy-split (waves 0/1: dy 0..15, waves 2/3: dy 16..30)
//     over the same shared LDS images -> 16 waves/CU; accumulator join via LDS.
// (2) XCD-chunked block swizzle so the 16 batch-blocks of a channel (sharing
//     that channel's B-fragment table) stay on one XCD's L2.
// Data layout unchanged from r4: quad-permuted f16 images (1 ds_read_b128 per
// A fragment), per-channel precomputed B Toeplitz fragments in global scratch.

#define C_     192
#define BS_    16
#define HW_    4096
#define KS_    31
#define NT_    256

#define IROWS_ 94
#define ISTR_  104                  // f16 per row (208 B, 16B-aligned rows)
#define IMGSZ_ (IROWS_ * ISTR_)     // 9776 f16 per image
#define NFRAG_ 160                  // per dy: l5(2) x s81(80)
#define BF_PER_C_ (KS_ * NFRAG_ * 8)             // 39,680 f16 per channel
#define BF_BYTES_ ((size_t)C_ * BF_PER_C_ * 2)   // 15,237,120 B

typedef _Float16 f16;
typedef _Float16 f16x4 __attribute__((ext_vector_type(4)));
typedef _Float16 f16x8 __attribute__((ext_vector_type(8)));
typedef float    f32x16 __attribute__((ext_vector_type(16)));

// ---------------------------------------------------------------- build B ----
// frag fi = ((c*31 + dy)*2 + l5)*80 + s81, s = s81-31 = 16*kc - l31.
// slot j holds w[dy][s + 4*l5 + (j&3) + 8*(j>>2) - 1] (0 outside [0,31)).
__global__ __launch_bounds__(256)
void build_bfrags(const float* __restrict__ wts, f16* __restrict__ bf)
{
    const int fi = blockIdx.x * 256 + threadIdx.x;
    if (fi >= C_ * KS_ * NFRAG_) return;
    const int s81 = fi % 80;
    int rest = fi / 80;
    const int l5 = rest & 1; rest >>= 1;
    const int dy = rest % KS_;
    const int c  = rest / KS_;
    const float* wrow = wts + (size_t)c * (KS_ * KS_) + dy * KS_;
    const int s = s81 - 31;
    f16x8 o;
#pragma unroll
    for (int j = 0; j < 8; ++j) {
        const int tap = s + 4 * l5 + (j & 3) + 8 * (j >> 2) - 1;
        o[j] = (tap >= 0 && tap < KS_) ? (f16)expm1f(wrow[tap]) : (f16)0.f;
    }
    *reinterpret_cast<f16x8*>(bf + (size_t)fi * 8) = o;
}

// ------------------------------------------------------------- main (fast) ---
__global__ __launch_bounds__(NT_, 4)
void aft_mfma3(const float* __restrict__ qkv,
               const f16* __restrict__ bf,
               float* __restrict__ out)
{
    __shared__ __align__(16) f16 IMG[2 * IMGSZ_];   // [0]=e image, [1]=kv image
    __shared__ float red[12];

    // XCD-chunked swizzle: original IDs {x, x+8, ...} (one XCD) -> contiguous
    // work ids -> each channel's 16 batch-blocks share one XCD L2.
    const int bid  = blockIdx.x;
    const int work = (bid & 7) * (BS_ * C_ / 8) + (bid >> 3);
    const int c = work >> 4;                 // c-major: 16 works share bf[c]
    const int b = work & 15;
    const float* qrow = qkv + ((size_t)b * (3 * C_) + c) * HW_;
    const float* krow = qrow + (size_t)C_ * HW_;
    const float* vrow = qrow + (size_t)(2 * C_) * HW_;
    float*       orow = out + ((size_t)b * C_ + c) * HW_;

    const int t = threadIdx.x, lane = t & 63, wid = t >> 6;
    const int l5 = lane >> 5, l31 = lane & 31;

    // zero both images (pads must be 0)
    uint4* I4 = reinterpret_cast<uint4*>(IMG);
    for (int i = t; i < (2 * IMGSZ_) / 8; i += NT_) I4[i] = make_uint4(0u, 0u, 0u, 0u);

    // ---- phase 1: softmax max (each thread: 4 float4 = 16 values) ----
    float pm = -3.0e38f;
#pragma unroll
    for (int i = 0; i < 4; ++i) {
        float4 k4 = ((const float4*)krow)[t + NT_ * i];
        pm = fmaxf(pm, fmaxf(fmaxf(k4.x, k4.y), fmaxf(k4.z, k4.w)));
    }
#pragma unroll
    for (int s = 32; s; s >>= 1) pm = fmaxf(pm, __shfl_xor(pm, s));
    if (lane == 0) red[wid] = pm;
    __syncthreads();                        // fences zero-fill too
    const float m = fmaxf(fmaxf(red[0], red[1]), fmaxf(red[2], red[3]));

    // ---- phase 2: e = exp(k-m), kv = e*v -> permuted f16 images; Z, sumkv ----
    const int ry  = t >> 4;                 // image row comp 0..15
    const int rx4 = t & 15;                 // float4 slot in 64-wide row
    const int g   = 1 + (rx4 >> 2);         // 16-col group (data starts col 16)
    const int q   = rx4 & 3;
    const int qp  = (q == 1) ? 2 : (q == 2) ? 1 : q;   // quad perm 0,2,1,3
    float zs = 0.f, skv = 0.f;
#pragma unroll
    for (int i = 0; i < 4; ++i) {
        float4 k4 = ((const float4*)krow)[t + NT_ * i];
        float4 v4 = ((const float4*)vrow)[t + NT_ * i];
        float e0 = __expf(k4.x - m), e1 = __expf(k4.y - m);
        float e2 = __expf(k4.z - m), e3 = __expf(k4.w - m);
        zs += (e0 + e1) + (e2 + e3);
        float a0 = e0 * v4.x, a1 = e1 * v4.y, a2 = e2 * v4.z, a3 = e3 * v4.w;
        skv += (a0 + a1) + (a2 + a3);
        const int row = ry + 16 * i + 15;
        f16* pE = (f16*)((char*)IMG + row * (ISTR_ * 2) + g * 32 + qp * 8);
        f16x4 he; he[0] = (f16)e0; he[1] = (f16)e1; he[2] = (f16)e2; he[3] = (f16)e3;
        f16x4 hk; hk[0] = (f16)a0; hk[1] = (f16)a1; hk[2] = (f16)a2; hk[3] = (f16)a3;
        *reinterpret_cast<f16x4*>(pE) = he;
        *reinterpret_cast<f16x4*>(pE + IMGSZ_) = hk;
    }
#pragma unroll
    for (int s = 32; s; s >>= 1) { zs += __shfl_xor(zs, s); skv += __shfl_xor(skv, s); }
    if (lane == 0) { red[4 + wid] = zs; red[8 + wid] = skv; }
    __syncthreads();                        // images + sums ready
    const float Z     = (red[4] + red[5]) + (red[6] + red[7]);
    const float sumkv = (red[8] + red[9]) + (red[10] + red[11]);

    // ---- fused conv loop, dy-split across wave pairs ----
    // wave wid: rowhalf = wid&1 (output rows 32*rowhalf..+32),
    //           dyhalf  = wid>>1 (dy in [16*dyhalf, dyhalf?31:16))
    const int rowhalf = wid & 1;
    const int dyh     = wid >> 1;
    const int dy0     = dyh * 16;
    const int dyEnd   = dyh ? KS_ : 16;

    f32x16 aE0, aE1, aK0, aK1;
#pragma unroll
    for (int r = 0; r < 16; ++r) { aE0[r] = 0.f; aE1[r] = 0.f; aK0[r] = 0.f; aK1[r] = 0.f; }

    const f16* bl = bf + (size_t)c * BF_PER_C_ + l5 * 640 + (31 - l31) * 8;
    int abyte = (32 * rowhalf + l31 + dy0) * (ISTR_ * 2) + l5 * 16;

    f16x8 Bc[4];
#pragma unroll
    for (int kc = 0; kc < 4; ++kc)
        Bc[kc] = *reinterpret_cast<const f16x8*>(bl + dy0 * (NFRAG_ * 8) + kc * 128);

#pragma unroll 1
    for (int dy = dy0; dy < dyEnd; ++dy) {
        // prefetch next-dy B (global, L2-hot)
        const int dyn = (dy + 1 < dyEnd) ? dy + 1 : dy;
        const f16* bln = bl + dyn * (NFRAG_ * 8);
        f16x8 Bn[4];
#pragma unroll
        for (int kc = 0; kc < 4; ++kc)
            Bn[kc] = *reinterpret_cast<const f16x8*>(bln + kc * 128);

        f16x8 AE[6], AK[6];
        const char* ap = (const char*)IMG + abyte;
#pragma unroll
        for (int cc = 0; cc < 6; ++cc) {
            AE[cc] = *reinterpret_cast<const f16x8*>(ap + cc * 32);
            AK[cc] = *reinterpret_cast<const f16x8*>(ap + cc * 32 + IMGSZ_ * 2);
        }
#pragma unroll
        for (int kc = 0; kc < 4; ++kc) {
            aE0 = __builtin_amdgcn_mfma_f32_32x32x16_f16(AE[kc],     Bc[kc], aE0, 0, 0, 0);
            aE1 = __builtin_amdgcn_mfma_f32_32x32x16_f16(AE[kc + 2], Bc[kc], aE1, 0, 0, 0);
            aK0 = __builtin_amdgcn_mfma_f32_32x32x16_f16(AK[kc],     Bc[kc], aK0, 0, 0, 0);
            aK1 = __builtin_amdgcn_mfma_f32_32x32x16_f16(AK[kc + 2], Bc[kc], aK1, 0, 0, 0);
        }
#pragma unroll
        for (int kc = 0; kc < 4; ++kc) Bc[kc] = Bn[kc];
        abyte += ISTR_ * 2;
    }
    __syncthreads();                        // all conv reads of IMG complete

    // ---- join: waves 2/3 dump accs into (dead) IMG, waves 0/1 add ----
    // per-lane slot: 64 f32 at stride 68 (16B-aligned, bank-spread)
    float* REDU = (float*)IMG;              // 128 lanes * 68 * 4B = 34,816 B
    if (wid >= 2) {
        float* p = REDU + ((wid - 2) * 64 + lane) * 68;
        const float* a0 = (const float*)&aE0;
        const float* a1 = (const float*)&aE1;
        const float* a2 = (const float*)&aK0;
        const float* a3 = (const float*)&aK1;
#pragma unroll
        for (int j2 = 0; j2 < 4; ++j2) {
            ((float4*)p)[j2 + 0]  = ((const float4*)a0)[j2];
            ((float4*)p)[j2 + 4]  = ((const float4*)a1)[j2];
            ((float4*)p)[j2 + 8]  = ((const float4*)a2)[j2];
            ((float4*)p)[j2 + 12] = ((const float4*)a3)[j2];
        }
    }
    __syncthreads();
    if (wid < 2) {
        const float* p = REDU + (wid * 64 + lane) * 68;
#pragma unroll
        for (int r = 0; r < 16; ++r) {
            aE0[r] += p[r];
            aE1[r] += p[16 + r];
            aK0[r] += p[32 + r];
            aK1[r] += p[48 + r];
        }

        // ---- epilogue: out = (kv_c + sumkv) / ((k_c + Z(1+1e-8)) * (1+e^-q))
        const int yb = 32 * rowhalf + 4 * l5;
#pragma unroll
        for (int tt = 0; tt < 2; ++tt) {
            const f32x16& ke = tt ? aE1 : aE0;
            const f32x16& kv = tt ? aK1 : aK0;
            const int x = 32 * tt + l31;
#pragma unroll
            for (int r = 0; r < 16; ++r) {
                const int y = yb + (r & 3) + 8 * (r >> 2);
                const int idx = y * 64 + x;
                const float qv = qrow[idx];
                const float den = (ke[r] + Z + Z * 1e-8f) * (1.f + __expf(-qv));
                orow[idx] = (kv[r] + sumkv) * __builtin_amdgcn_rcpf(den);
            }
        }
    }
}

// ------------------------------------------- fallback (round-3, ws too small)
#define FB_IROWS_ 94
#define FB_ISTR_  100
#define FB_WCOLS_ 96

__device__ __forceinline__ void conv_pass_fb(const f16* __restrict__ img,
                                             const unsigned int* __restrict__ wp,
                                             int lane, int ybase,
                                             f32x16* acc0, f32x16* acc1)
{
    const int l5  = lane >> 5;
    const int l31 = lane & 31;
    int aoff = (ybase + l31) * FB_ISTR_ + 4 * l5;
    const unsigned int* bp0 = wp + (32 + 4 * l5 - l31);
#pragma unroll 1
    for (int dy = 0; dy < KS_; ++dy) {
        f16x8 A[6];
        const f16* ap = img + aoff;
#pragma unroll
        for (int cc = 0; cc < 6; ++cc) {
            f16x4 lo = *(const f16x4*)(ap + cc * 16);
            f16x4 hi = *(const f16x4*)(ap + cc * 16 + 8);
            A[cc] = __builtin_shufflevector(lo, hi, 0, 1, 2, 3, 4, 5, 6, 7);
        }
        const unsigned int* bp = bp0 + dy * FB_WCOLS_;
#pragma unroll
        for (int kc = 0; kc < 4; ++kc) {
            uint4 bw;
            bw.x = bp[kc * 16 + 0];
            bw.y = bp[kc * 16 + 2];
            bw.z = bp[kc * 16 + 8];
            bw.w = bp[kc * 16 + 10];
            f16x8 B = __builtin_bit_cast(f16x8, bw);
            *acc0 = __builtin_amdgcn_mfma_f32_32x32x16_f16(A[kc],     B, *acc0, 0, 0, 0);
            *acc1 = __builtin_amdgcn_mfma_f32_32x32x16_f16(A[kc + 2], B, *acc1, 0, 0, 0);
        }
        aoff += FB_ISTR_;
    }
}

__global__ __launch_bounds__(128, 2)
void aft_mfma(const float* __restrict__ qkv,
              const float* __restrict__ wts,
              float* __restrict__ out)
{
    __shared__ __align__(16) f16 IMGF[FB_IROWS_ * FB_ISTR_];
    __shared__ unsigned int WP[KS_ * FB_WCOLS_];
    __shared__ float red[8];

    const int bc = blockIdx.x;
    const int b  = bc / C_;
    const int c  = bc - b * C_;
    const float* qrow = qkv + ((size_t)b * (3 * C_) + c) * HW_;
    const float* krow = qrow + (size_t)C_ * HW_;
    const float* vrow = qrow + (size_t)(2 * C_) * HW_;
    float*       orow = out + ((size_t)b * C_ + c) * HW_;

    const int t = threadIdx.x, lane = t & 63, wid = t >> 6;

    unsigned int* IMGu = (unsigned int*)IMGF;
    for (int i = t; i < (FB_IROWS_ * FB_ISTR_) / 2; i += 128) IMGu[i] = 0u;
    const float* wch = wts + (size_t)c * (KS_ * KS_);
    for (int i = t; i < KS_ * FB_WCOLS_; i += 128) {
        const int dy = i / FB_WCOLS_, cw = i - dy * FB_WCOLS_;
        const int d0 = cw - 33, d1 = cw - 32;
        const float w0 = (d0 >= 0 && d0 < KS_) ? expm1f(wch[dy * KS_ + d0]) : 0.f;
        const float w1 = (d1 >= 0 && d1 < KS_) ? expm1f(wch[dy * KS_ + d1]) : 0.f;
        union { unsigned int u; f16 h[2]; } pk;
        pk.h[0] = (f16)w0; pk.h[1] = (f16)w1;
        WP[i] = pk.u;
    }

    float kvv[32];
    float pm = -3.0e38f;
#pragma unroll
    for (int i = 0; i < 8; ++i) {
        float4 v = ((const float4*)krow)[t + 128 * i];
        kvv[4*i+0] = v.x; kvv[4*i+1] = v.y; kvv[4*i+2] = v.z; kvv[4*i+3] = v.w;
        pm = fmaxf(pm, fmaxf(fmaxf(v.x, v.y), fmaxf(v.z, v.w)));
    }
#pragma unroll
    for (int s = 32; s; s >>= 1) pm = fmaxf(pm, __shfl_xor(pm, s));
    if (lane == 0) red[wid] = pm;
    __syncthreads();
    const float m = fmaxf(red[0], red[1]);

    const int ry = t >> 4;
    const int rx = (t & 15) * 4;
    float ps = 0.f;
#pragma unroll
    for (int i = 0; i < 8; ++i) {
        f16x4 h;
#pragma unroll
        for (int e = 0; e < 4; ++e) {
            float ev = __expf(kvv[4*i+e] - m);
            ps += ev;
            h[e] = (f16)ev;
        }
        *(f16x4*)(&IMGF[(ry + 8 * i + 15) * FB_ISTR_ + rx + 16]) = h;
    }
#pragma unroll
    for (int s = 32; s; s >>= 1) ps += __shfl_xor(ps, s);
    if (lane == 0) red[2 + wid] = ps;
    __syncthreads();
    const float Z = red[2] + red[3];

    f32x16 accA0, accA1;
#pragma unroll
    for (int r = 0; r < 16; ++r) { accA0[r] = 0.f; accA1[r] = 0.f; }
    conv_pass_fb(IMGF, WP, lane, 32 * wid, &accA0, &accA1);
    __syncthreads();

    float skv = 0.f;
#pragma unroll
    for (int i = 0; i < 8; ++i) {
        float4 v = ((const float4*)vrow)[t + 128 * i];
        f16* pp = &IMGF[(ry + 8 * i + 15) * FB_ISTR_ + rx + 16];
        f16x4 h = *(f16x4*)pp;
        float a0 = (float)h[0] * v.x;
        float a1 = (float)h[1] * v.y;
        float a2 = (float)h[2] * v.z;
        float a3 = (float)h[3] * v.w;
        skv += (a0 + a1) + (a2 + a3);
        h[0] = (f16)a0; h[1] = (f16)a1; h[2] = (f16)a2; h[3] = (f16)a3;
        *(f16x4*)pp = h;
    }
#pragma unroll
    for (int s = 32; s; s >>= 1) skv += __shfl_xor(skv, s);
    if (lane == 0) red[4 + wid] = skv;
    __syncthreads();
    const float sumkv = red[4] + red[5];

    f32x16 accB0, accB1;
#pragma unroll
    for (int r = 0; r < 16; ++r) { accB0[r] = 0.f; accB1[r] = 0.f; }
    conv_pass_fb(IMGF, WP, lane, 32 * wid, &accB0, &accB1);

    const int yb = 32 * wid + 4 * (lane >> 5);
    const int l31 = lane & 31;
#pragma unroll
    for (int tt = 0; tt < 2; ++tt) {
        const f32x16& ka = tt ? accA1 : accA0;
        const f32x16& va = tt ? accB1 : accB0;
        const int x = 32 * tt + l31;
#pragma unroll
        for (int r = 0; r < 16; ++r) {
            const int y = yb + (r & 3) + 8 * (r >> 2);
            const int idx = y * 64 + x;
            const float qv = qrow[idx];
            const float den = (ka[r] + Z + Z * 1e-8f) * (1.f + __expf(-qv));
            orow[idx] = (va[r] + sumkv) * __builtin_amdgcn_rcpf(den);
        }
    }
}

// ------------------------------------------------------------------ launch ---
extern "C" void kernel_launch(void* const* d_in, const int* in_sizes, int n_in,
                              void* d_out, int out_size, void* d_ws, size_t ws_size,
                              hipStream_t stream)
{
    const float* qkv = (const float*)d_in[0];   // (16, 576, 4096) fp32
    const float* wts = (const float*)d_in[1];   // (192, 1, 31, 31) fp32
    float* out       = (float*)d_out;           // (16, 192, 4096) fp32
    (void)in_sizes; (void)n_in; (void)out_size;

    if (ws_size >= BF_BYTES_ && d_ws != nullptr) {
        f16* bfr = (f16*)d_ws;
        const int total = C_ * KS_ * NFRAG_;
        build_bfrags<<<dim3((total + 255) / 256), dim3(256), 0, stream>>>(wts, bfr);
        aft_mfma3<<<dim3(BS_ * C_), dim3(NT_), 0, stream>>>(qkv, bfr, out);
    } else {
        aft_mfma<<<dim3(BS_ * C_), dim3(128), 0, stream>>>(qkv, wts, out);
    }
}